// Round 1
// 606.960 us; speedup vs baseline: 1.0100x; 1.0100x over previous
//
#include <hip/hip_runtime.h>

// Problem constants
#define B_ 2
#define S_ 5
#define C_ 256
#define H_ 192
#define W_ 192
#define K_ 7
#define NH_ 28
#define NW_ 28
#define HID_ 16

// g layout: [b][n][m][s][c]  -> ((b*NH+n)*NW+m)*(S_*C_) + s*C_ + c
// wt layout: [b][s][n][m]    -> ((b*S_+s)*NH+n)*NW + m

// Kernel 1: per-window means. One block per (b,s,c,n) band; 256 threads.
// Stage the 7x192 band (contiguous in memory) via float4, then 196 threads
// reduce 7 cols each (stride-7 LDS reads, coprime with 32 banks), then 28
// threads sum across the 7 rows and write g.
__global__ void k_means(const float* __restrict__ x, float* __restrict__ g) {
    int idx = blockIdx.x;
    int n = idx % NH_; idx /= NH_;
    int c = idx % C_;  idx /= C_;
    int s = idx % S_;  idx /= S_;
    int b = idx;
    int r0 = n * K_;
    int nr = (H_ - r0 < K_) ? (H_ - r0) : K_;          // 7, or 3 for n=27
    const float* src = x + ((size_t)((b * S_ + s) * C_ + c)) * (H_ * W_)
                         + (size_t)r0 * W_;            // band is contiguous
    __shared__ __align__(16) float band[K_ * W_];      // 1344 floats
    __shared__ float psum[K_ * NW_];                   // 196

    const float4* src4 = reinterpret_cast<const float4*>(src);
    float4* band4 = reinterpret_cast<float4*>(band);
    int nf4 = nr * (W_ / 4);                           // 336 or 144
    for (int l = threadIdx.x; l < nf4; l += blockDim.x) band4[l] = src4[l];
    __syncthreads();

    int t = threadIdx.x;
    if (t < K_ * NW_) {
        int kh = t / NW_, m = t % NW_;
        float v = 0.f;
        if (kh < nr) {
            int c0 = m * K_;
#pragma unroll
            for (int d = 0; d < K_; ++d) {
                int cc = c0 + d;
                if (cc < W_) v += band[kh * W_ + cc];  // pad cols contribute 0
            }
        }
        psum[t] = v;
    }
    __syncthreads();
    if (t < NW_) {
        float ssum = 0.f;
#pragma unroll
        for (int kh = 0; kh < K_; ++kh) ssum += psum[kh * NW_ + t];
        g[((size_t)((b * NH_ + n) * NW_ + t)) * (S_ * C_) + s * C_ + c] =
            ssum * (1.0f / 49.0f);
    }
}

// Kernel 2: tiny MLP over C + softmax over S. One block per (b,n,m) site,
// 5 waves (one per slice). Butterfly wave-reduction for the 256-dot products.
__global__ void k_mlp(const float* __restrict__ g, const float* __restrict__ w1,
                      const float* __restrict__ b1, const float* __restrict__ w2,
                      const float* __restrict__ b2, const float* __restrict__ sl,
                      float* __restrict__ wt) {
    int site = blockIdx.x;             // [0, B*NH*NW)
    int m = site % NW_;
    int n = (site / NW_) % NH_;
    int b = site / (NW_ * NH_);
    int s = threadIdx.x >> 6;          // wave index = slice
    int lane = threadIdx.x & 63;
    const float* gv = g + (size_t)site * (S_ * C_) + s * C_;
    float x0 = gv[lane];
    float x1 = gv[lane + 64];
    float x2 = gv[lane + 128];
    float x3 = gv[lane + 192];
    float logit = 0.f;
#pragma unroll
    for (int jj = 0; jj < HID_; ++jj) {
        const float* wr = w1 + jj * C_;
        float p = wr[lane] * x0 + wr[lane + 64] * x1 +
                  wr[lane + 128] * x2 + wr[lane + 192] * x3;
#pragma unroll
        for (int o = 1; o < 64; o <<= 1) p += __shfl_xor(p, o, 64);
        float h = p + b1[jj];
        h = h > 0.f ? h : 0.f;
        logit = fmaf(w2[jj], h, logit);
    }
    __shared__ float lg[S_];
    if (lane == 0) lg[s] = logit + b2[0] + sl[s];
    __syncthreads();
    if (threadIdx.x < S_) {
        int ss = threadIdx.x;
        float mx = lg[0];
#pragma unroll
        for (int t = 1; t < S_; ++t) mx = fmaxf(mx, lg[t]);
        float den = 0.f;
#pragma unroll
        for (int t = 0; t < S_; ++t) den += expf(lg[t] - mx);
        wt[((b * S_ + ss) * NH_ + n) * NW_ + m] = expf(lg[ss] - mx) / den;
    }
}

// Kernel 3: weighted gather into interleaved output layout.
// One block per (b,c,n) band; 448 threads (7 waves). Stage the 7x192 source
// band of all 5 slices in LDS via float4 (each band is contiguous), then emit
// all 7 output rows i = kh*28+n with coalesced writes. The i->r map is a
// bijection per band, so x is read exactly once overall.
#define TPB_OUT 448
__global__ void __launch_bounds__(TPB_OUT)
k_out(const float* __restrict__ x, const float* __restrict__ wt,
      float* __restrict__ out) {
    int idx = blockIdx.x;
    int n = idx % NH_; idx /= NH_;
    int c = idx % C_;  idx /= C_;
    int b = idx;
    int r0 = n * K_;
    int nr = (H_ - r0 < K_) ? (H_ - r0) : K_;          // 7, or 3 for n=27
    __shared__ __align__(16) float band[S_][K_ * W_];  // 26880 B
    __shared__ float wrow[S_][NW_];

    int t = threadIdx.x;
    int nf4s = nr * (W_ / 4);                          // per-slice float4 count
    for (int l = t; l < S_ * nf4s; l += TPB_OUT) {
        int s = l / nf4s, f = l % nf4s;
        const float4* src4 = reinterpret_cast<const float4*>(
            x + ((size_t)((b * S_ + s) * C_ + c)) * (H_ * W_)
              + (size_t)r0 * W_);
        reinterpret_cast<float4*>(band[s])[f] = src4[f];
    }
    if (t < S_ * NW_) {
        int s = t / NW_, m = t % NW_;
        wrow[s][m] = wt[((b * S_ + s) * NH_ + n) * NW_ + m];
    }
    __syncthreads();

    // 7 output rows x 192 cols; kh is wave-uniform (192 = 3 waves, 448 % 64 == 0)
    for (int u = t; u < K_ * W_; u += TPB_OUT) {
        int kh = u / W_, j = u % W_;
        int i = kh * NH_ + n;                          // output row
        if (i >= H_) continue;                         // cropped (n=27, kh=6)
        int r = r0 + kh;                               // source row
        float val = 0.f;
        if (r < H_) {
            int m = j % NW_, kw = j / NW_;
            int col = m * K_ + kw;                     // source col
            if (col < W_) {
#pragma unroll
                for (int s = 0; s < S_; ++s)
                    val = fmaf(wrow[s][m], band[s][kh * W_ + col], val);
            }
        }
        out[(((size_t)(b * C_ + c)) * H_ + i) * (size_t)W_ + j] = val;
    }
}

extern "C" void kernel_launch(void* const* d_in, const int* in_sizes, int n_in,
                              void* d_out, int out_size, void* d_ws, size_t ws_size,
                              hipStream_t stream) {
    const float* x  = (const float*)d_in[0];
    const float* w1 = (const float*)d_in[1];
    const float* b1 = (const float*)d_in[2];
    const float* w2 = (const float*)d_in[3];
    const float* b2 = (const float*)d_in[4];
    const float* sl = (const float*)d_in[5];
    float* out = (float*)d_out;

    float* g  = (float*)d_ws;                               // B*NH*NW*S*C floats = ~8 MB
    float* wt = g + (size_t)B_ * NH_ * NW_ * S_ * C_;       // B*S*NH*NW floats

    k_means<<<B_ * S_ * C_ * NH_, 256, 0, stream>>>(x, g);
    k_mlp<<<B_ * NH_ * NW_, 5 * 64, 0, stream>>>(g, w1, b1, w2, b2, sl, wt);
    k_out<<<B_ * C_ * NH_, TPB_OUT, 0, stream>>>(x, wt, out);
}

// Round 2
// 597.118 us; speedup vs baseline: 1.0266x; 1.0165x over previous
//
#include <hip/hip_runtime.h>

// Problem constants
#define B_ 2
#define S_ 5
#define C_ 256
#define H_ 192
#define W_ 192
#define K_ 7
#define NH_ 28
#define NW_ 28
#define HID_ 16

// g layout: [b][n][m][s][c]  -> ((b*NH+n)*NW+m)*(S_*C_) + s*C_ + c
// wt layout: [b][s][n][m]    -> ((b*S_+s)*NH+n)*NW + m
//
// All three kernels are launched PER BATCH b: x_b is 188.7 MB < 256 MB L3,
// so k_out(b) re-reads x_b from Infinity Cache instead of HBM. out is
// written with non-temporal stores to avoid evicting x_b between phases.

// Kernel 1: per-window means. One block per (s,c,n) band of batch b; 256
// threads. Stage the 7x192 band (contiguous) via float4, reduce 7 cols per
// thread (stride-7 LDS, coprime with 32 banks), then 28 threads sum rows.
__global__ void k_means(const float* __restrict__ x, float* __restrict__ g,
                        int b) {
    int idx = blockIdx.x;
    int n = idx % NH_; idx /= NH_;
    int c = idx % C_;  idx /= C_;
    int s = idx;
    int r0 = n * K_;
    int nr = (H_ - r0 < K_) ? (H_ - r0) : K_;          // 7, or 3 for n=27
    const float* src = x + ((size_t)((b * S_ + s) * C_ + c)) * (H_ * W_)
                         + (size_t)r0 * W_;            // band is contiguous
    __shared__ __align__(16) float band[K_ * W_];      // 1344 floats
    __shared__ float psum[K_ * NW_];                   // 196

    const float4* src4 = reinterpret_cast<const float4*>(src);
    float4* band4 = reinterpret_cast<float4*>(band);
    int nf4 = nr * (W_ / 4);                           // 336 or 144
    for (int l = threadIdx.x; l < nf4; l += blockDim.x) band4[l] = src4[l];
    __syncthreads();

    int t = threadIdx.x;
    if (t < K_ * NW_) {
        int kh = t / NW_, m = t % NW_;
        float v = 0.f;
        if (kh < nr) {
            int c0 = m * K_;
#pragma unroll
            for (int d = 0; d < K_; ++d) {
                int cc = c0 + d;
                if (cc < W_) v += band[kh * W_ + cc];  // pad cols contribute 0
            }
        }
        psum[t] = v;
    }
    __syncthreads();
    if (t < NW_) {
        float ssum = 0.f;
#pragma unroll
        for (int kh = 0; kh < K_; ++kh) ssum += psum[kh * NW_ + t];
        g[((size_t)((b * NH_ + n) * NW_ + t)) * (S_ * C_) + s * C_ + c] =
            ssum * (1.0f / 49.0f);
    }
}

// Kernel 2: tiny MLP over C + softmax over S. One block per (n,m) site of
// batch b, 5 waves (one per slice). Butterfly wave-reduction for dots.
__global__ void k_mlp(const float* __restrict__ g, const float* __restrict__ w1,
                      const float* __restrict__ b1, const float* __restrict__ w2,
                      const float* __restrict__ b2, const float* __restrict__ sl,
                      float* __restrict__ wt, int b) {
    int site = blockIdx.x;             // [0, NH*NW)
    int m = site % NW_;
    int n = site / NW_;
    int s = threadIdx.x >> 6;          // wave index = slice
    int lane = threadIdx.x & 63;
    const float* gv = g + ((size_t)(b * NH_ * NW_ + site)) * (S_ * C_) + s * C_;
    float x0 = gv[lane];
    float x1 = gv[lane + 64];
    float x2 = gv[lane + 128];
    float x3 = gv[lane + 192];
    float logit = 0.f;
#pragma unroll
    for (int jj = 0; jj < HID_; ++jj) {
        const float* wr = w1 + jj * C_;
        float p = wr[lane] * x0 + wr[lane + 64] * x1 +
                  wr[lane + 128] * x2 + wr[lane + 192] * x3;
#pragma unroll
        for (int o = 1; o < 64; o <<= 1) p += __shfl_xor(p, o, 64);
        float h = p + b1[jj];
        h = h > 0.f ? h : 0.f;
        logit = fmaf(w2[jj], h, logit);
    }
    __shared__ float lg[S_];
    if (lane == 0) lg[s] = logit + b2[0] + sl[s];
    __syncthreads();
    if (threadIdx.x < S_) {
        int ss = threadIdx.x;
        float mx = lg[0];
#pragma unroll
        for (int t = 1; t < S_; ++t) mx = fmaxf(mx, lg[t]);
        float den = 0.f;
#pragma unroll
        for (int t = 0; t < S_; ++t) den += expf(lg[t] - mx);
        wt[((b * S_ + ss) * NH_ + n) * NW_ + m] = expf(lg[ss] - mx) / den;
    }
}

// Kernel 3: weighted gather into interleaved output layout.
// One block per (c,n) band of batch b; 448 threads (7 waves). Stage the
// 7x192 source band of all 5 slices in LDS via float4 (x_b should be
// L3-resident from k_means), emit all 7 output rows i = kh*28+n with
// coalesced NON-TEMPORAL writes (out is never re-read; don't evict x_b).
#define TPB_OUT 448
__global__ void __launch_bounds__(TPB_OUT)
k_out(const float* __restrict__ x, const float* __restrict__ wt,
      float* __restrict__ out, int b) {
    int idx = blockIdx.x;
    int n = idx % NH_; idx /= NH_;
    int c = idx;
    int r0 = n * K_;
    int nr = (H_ - r0 < K_) ? (H_ - r0) : K_;          // 7, or 3 for n=27
    __shared__ __align__(16) float band[S_][K_ * W_];  // 26880 B
    __shared__ float wrow[S_][NW_];

    int t = threadIdx.x;
    int nf4s = nr * (W_ / 4);                          // per-slice float4 count
    for (int l = t; l < S_ * nf4s; l += TPB_OUT) {
        int s = l / nf4s, f = l % nf4s;
        const float4* src4 = reinterpret_cast<const float4*>(
            x + ((size_t)((b * S_ + s) * C_ + c)) * (H_ * W_)
              + (size_t)r0 * W_);
        reinterpret_cast<float4*>(band[s])[f] = src4[f];
    }
    if (t < S_ * NW_) {
        int s = t / NW_, m = t % NW_;
        wrow[s][m] = wt[((b * S_ + s) * NH_ + n) * NW_ + m];
    }
    __syncthreads();

    // 7 output rows x 192 cols; 1344 = 3 * 448 -> exactly 3 iters/thread
    for (int u = t; u < K_ * W_; u += TPB_OUT) {
        int kh = u / W_, j = u % W_;
        int i = kh * NH_ + n;                          // output row
        if (i >= H_) continue;                         // cropped (n=27, kh=6)
        int r = r0 + kh;                               // source row
        float val = 0.f;
        if (r < H_) {
            int m = j % NW_, kw = j / NW_;
            int col = m * K_ + kw;                     // source col
            if (col < W_) {
#pragma unroll
                for (int s = 0; s < S_; ++s)
                    val = fmaf(wrow[s][m], band[s][kh * W_ + col], val);
            }
        }
        __builtin_nontemporal_store(
            val, out + (((size_t)(b * C_ + c)) * H_ + i) * (size_t)W_ + j);
    }
}

extern "C" void kernel_launch(void* const* d_in, const int* in_sizes, int n_in,
                              void* d_out, int out_size, void* d_ws, size_t ws_size,
                              hipStream_t stream) {
    const float* x  = (const float*)d_in[0];
    const float* w1 = (const float*)d_in[1];
    const float* b1 = (const float*)d_in[2];
    const float* w2 = (const float*)d_in[3];
    const float* b2 = (const float*)d_in[4];
    const float* sl = (const float*)d_in[5];
    float* out = (float*)d_out;

    float* g  = (float*)d_ws;                               // B*NH*NW*S*C floats = ~8 MB
    float* wt = g + (size_t)B_ * NH_ * NW_ * S_ * C_;       // B*S*NH*NW floats

    for (int b = 0; b < B_; ++b) {
        k_means<<<S_ * C_ * NH_, 256, 0, stream>>>(x, g, b);
        k_mlp<<<NH_ * NW_, 5 * 64, 0, stream>>>(g, w1, b1, w2, b2, sl, wt, b);
        k_out<<<C_ * NH_, TPB_OUT, 0, stream>>>(x, wt, out, b);
    }
}